// Round 5
// baseline (34.163 us; speedup 1.0000x reference)
//
#include <hip/hip_runtime.h>
#include <math.h>

#define NN 1024
#define BTH 256
#define NT 16              // NN/64 tile-chunks per row
#define NTILES 136         // NT*(NT+1)/2 upper-triangle 64x64 tiles
#define TBLK 34            // tile blocks per batch (4 waves = 4 tiles each)

// f(i,j) = softplus(x) - t*x  (t = [ri>rj]), gated by valid = [ri!=rj].
// Identity: sp(x) - t*x = sp((1-2t)x)  =>  symmetric: f(i,j) = f(j,i).
__device__ __forceinline__ float pair_f(float pi, float ri, float pj, float rj) {
    const float x = pi - pj;
    const float y = (ri > rj) ? -x : x;
    const float e = __expf(-fabsf(y));
    const float f = fmaxf(y, 0.0f) + __logf(1.0f + e);
    return (ri != rj) ? f : 0.0f;
}

// ---------------------------------------------------------------------------
// ONE kernel, grid = B + TBLK*B blocks:
//   blocks [0,B):        per-batch top-3 (registers), ballot histogram,
//                        weighted correction corr[b], valid count cntv[b]
//   blocks [B, B+34*B):  unweighted upper-triangle 64x64 tiles (barrier-free)
//   last-finished block: deterministic final reduction -> out[0]
// Ticket trick: (old+1) % gridDim.x == 0 fires exactly once per launch for ANY
// initial counter value (each launch advances ctr by exactly gridDim.x), so no
// counter reset / memset dispatch is needed and replays stay correct.
// ---------------------------------------------------------------------------
__global__ void __launch_bounds__(BTH)
fused_kernel(const float* __restrict__ pred, const float* __restrict__ rel,
             float* __restrict__ psum, float* __restrict__ corr,
             float* __restrict__ cntv, unsigned int* __restrict__ ctr,
             float* __restrict__ out, int B) {
    const int t = threadIdx.x;
    const int w = t >> 6, l = t & 63;
    const int blk = blockIdx.x;

    __shared__ float s_p[NN];
    __shared__ float s_r[NN];
    __shared__ float s_rv[3][4];
    __shared__ int   s_ri[3][4];
    __shared__ int   s_hist[4][5];
    __shared__ float s_red[4];
    __shared__ float s_l[32];
    __shared__ int   s_flag;

    if (blk < B) {
        // ---------------- top-k path: one block per batch ----------------
        const int b = blk;
        const size_t base = (size_t)b * NN;
        const float4 p4 = ((const float4*)(pred + base))[t];
        const float4 r4 = ((const float4*)(rel  + base))[t];
        ((float4*)s_p)[t] = p4;
        ((float4*)s_r)[t] = r4;

        // grade histogram via ballots (no atomics)
        for (int g = 0; g < 5; ++g) {
            const float gf = (float)g;
            int c = __popcll(__ballot(r4.x == gf)) + __popcll(__ballot(r4.y == gf))
                  + __popcll(__ballot(r4.z == gf)) + __popcll(__ballot(r4.w == gf));
            if (l == 0) s_hist[w][g] = c;
        }

        // top-3 from registers; tie-break: lower index wins (jax.lax.top_k)
        int w1 = -1, w2 = -1, w3 = -1;
        const int n0 = t * 4;
        for (int k = 0; k < 3; ++k) {
            float bv = -INFINITY;
            int   bi = NN;
            // ascending n + strict '>' keeps lowest index among own 4
            if (n0 + 0 != w1 && n0 + 0 != w2 && p4.x > bv) { bv = p4.x; bi = n0 + 0; }
            if (n0 + 1 != w1 && n0 + 1 != w2 && p4.y > bv) { bv = p4.y; bi = n0 + 1; }
            if (n0 + 2 != w1 && n0 + 2 != w2 && p4.z > bv) { bv = p4.z; bi = n0 + 2; }
            if (n0 + 3 != w1 && n0 + 3 != w2 && p4.w > bv) { bv = p4.w; bi = n0 + 3; }
            for (int off = 32; off > 0; off >>= 1) {
                const float ov = __shfl_xor(bv, off);
                const int   oi = __shfl_xor(bi, off);
                if (ov > bv || (ov == bv && oi < bi)) { bv = ov; bi = oi; }
            }
            if (l == 0) { s_rv[k][w] = bv; s_ri[k][w] = bi; }
            __syncthreads();
            bv = s_rv[k][0]; bi = s_ri[k][0];
            for (int q = 1; q < 4; ++q) {
                const float ov = s_rv[k][q]; const int oi = s_ri[k][q];
                if (ov > bv || (ov == bv && oi < bi)) { bv = ov; bi = oi; }
            }
            if (k == 0) w1 = bi; else if (k == 1) w2 = bi; else w3 = bi;
        }

        // unweighted rowsums over the 3 winners (s_p/s_r visible: synced above)
        float part = 0.0f;
        for (int k = 0; k < 3; ++k) {
            const int row = (k == 0) ? w1 : (k == 1) ? w2 : w3;
            const float pk = s_p[row], rk = s_r[row];
#pragma unroll
            for (int c = 0; c < 4; ++c) {
                const int j = t + c * BTH;
                part += pair_f(pk, rk, s_p[j], s_r[j]);
            }
        }
        for (int off = 32; off > 0; off >>= 1) part += __shfl_down(part, off);
        if (l == 0) s_red[w] = part;
        __syncthreads();
        if (t == 0) {
            const float R = s_red[0] + s_red[1] + s_red[2] + s_red[3];
            const float TT = 2.0f * (pair_f(s_p[w1], s_r[w1], s_p[w2], s_r[w2])
                                   + pair_f(s_p[w1], s_r[w1], s_p[w3], s_r[w3])
                                   + pair_f(s_p[w2], s_r[w2], s_p[w3], s_r[w3]));
            corr[b] = 2.0f * R + TT;   // W = 1 + m_i + m_j + m_i*m_j terms
            int s2 = 0;
            for (int g = 0; g < 5; ++g) {
                const int cg = s_hist[0][g] + s_hist[1][g] + s_hist[2][g] + s_hist[3][g];
                s2 += cg * cg;
            }
            cntv[b] = (float)(NN * NN - s2);
        }
    } else {
        // ---------------- tile path: one wave per 64x64 tile ----------------
        const int idx = blk - B;
        const int b = idx / TBLK;
        const int L = (idx % TBLK) * 4 + w;     // 0..135
        int rem = L, ti = 0;
        while (rem >= NT - ti) { rem -= NT - ti; ++ti; }
        const int tj = ti + rem;
        const size_t base = (size_t)b * NN;
        const int i0 = ti * 64, j0 = tj * 64;

        const float jp = pred[base + j0 + l];
        const float jr = rel [base + j0 + l];
        // per-wave private LDS segment (no block barrier; wave-lockstep + lgkmcnt)
        s_p[w * 64 + l] = pred[base + i0 + l];
        s_r[w * 64 + l] = rel [base + i0 + l];

        float acc = 0.0f;
        if (ti != tj) {
#pragma unroll 16
            for (int ii = 0; ii < 64; ++ii)
                acc += pair_f(s_p[w * 64 + ii], s_r[w * 64 + ii], jp, jr);
        } else {
#pragma unroll 16
            for (int ii = 0; ii < 64; ++ii) {
                const float f = pair_f(s_p[w * 64 + ii], s_r[w * 64 + ii], jp, jr);
                acc += (l > ii) ? f : 0.0f;     // strict upper triangle
            }
        }
        for (int off = 32; off > 0; off >>= 1) acc += __shfl_down(acc, off);
        if (l == 0) psum[(size_t)b * NTILES + L] = acc * 2.0f;  // both orders
    }

    // ---------------- last-block-done finalize ----------------
    __syncthreads();
    if (t == 0) {
        __threadfence();                               // release partials
        const unsigned int old = atomicAdd(ctr, 1u);
        s_flag = (((old + 1u) % (unsigned int)gridDim.x) == 0u) ? 1 : 0;
    }
    __syncthreads();
    if (s_flag) {
        __threadfence();                               // acquire partials
        const int bb = t >> 3;
        const int k  = t & 7;
        float s = 0.0f;
        if (bb < B) {
            for (int e = k; e < NTILES; e += 8) s += psum[(size_t)bb * NTILES + e];
        }
        s += __shfl_xor(s, 1);
        s += __shfl_xor(s, 2);
        s += __shfl_xor(s, 4);
        if (bb < B && k == 0) s_l[bb] = (s + corr[bb]) / (cntv[bb] + 1e-8f);
        __syncthreads();
        if (t == 0) {
            float m = 0.0f;
            for (int i = 0; i < B; ++i) m += s_l[i];
            out[0] = m / (float)B;
        }
    }
}

extern "C" void kernel_launch(void* const* d_in, const int* in_sizes, int n_in,
                              void* d_out, int out_size, void* d_ws, size_t ws_size,
                              hipStream_t stream) {
    const float* pred = (const float*)d_in[0];
    const float* rel  = (const float*)d_in[1];
    float* out = (float*)d_out;

    const int B = in_sizes[0] / NN;  // 32

    // ws: [ctr : 64B pad] | psum[B*NTILES] | corr[B] | cntv[B]
    unsigned int* ctr = (unsigned int*)d_ws;
    float* psum = (float*)((char*)d_ws + 64);
    float* corr = psum + (size_t)B * NTILES;
    float* cntv = corr + B;

    fused_kernel<<<B + TBLK * B, BTH, 0, stream>>>(pred, rel, psum, corr, cntv, ctr, out, B);
}